// Round 5
// baseline (294.683 us; speedup 1.0000x reference)
//
#include <hip/hip_runtime.h>

#define N_ROWS 131072
#define D_COLS 256
#define B_SEG  16
#define ROWS_PER_WAVE 16
#define BLK_THREADS 512                      // 8 waves/block
#define ROWS_PER_BLOCK (ROWS_PER_WAVE * BLK_THREADS / 64)   // 128
#define NBLK (N_ROWS / ROWS_PER_BLOCK)       // 1024

// Single fused kernel:
//  - one wave per 16 contiguous rows; lane l loads float4 at column 4*l
//  - block combines its 8 waves' (loss_pos, loss_neg) partials in LDS
//  - block stores its 32-float partial line acc[blockIdx][32] (no atomics)
//  - last block (ticket counter) reduces all partials -> out[0], resets ticket
__global__ __launch_bounds__(BLK_THREADS) void umse_fused(
    const float* __restrict__ input,
    const float* __restrict__ target,
    const int*   __restrict__ batch,
    float*       __restrict__ acc /* [NBLK][B_SEG*2] */,
    int*         __restrict__ ticket,
    float*       __restrict__ out) {

    __shared__ float lacc[B_SEG * 2];
    __shared__ float sums[16][B_SEG * 2];
    __shared__ int   isLast;
    const int tid  = threadIdx.x;
    const int lane = tid & 63;
    if (tid < B_SEG * 2) lacc[tid] = 0.f;
    __syncthreads();

    const int wave = (blockIdx.x * BLK_THREADS + tid) >> 6;
    const long row0 = (long)wave * ROWS_PER_WAVE;

    const float4* __restrict__ in4 = (const float4*)input;
    const float4* __restrict__ tg4 = (const float4*)target;

    const int b0 = batch[row0];
    const int b1 = batch[row0 + ROWS_PER_WAVE - 1];

    if (b0 == b1) {
        // ---- fast path: whole chunk in one segment (8177+ of 8192 waves) ----
        float rp0 = 0.f, rn0 = 0.f, rp1 = 0.f, rn1 = 0.f;
        float rp2 = 0.f, rn2 = 0.f, rp3 = 0.f, rn3 = 0.f;
        #pragma unroll
        for (int i = 0; i < ROWS_PER_WAVE; i += 4) {
            const long base = (row0 + i) * (D_COLS / 4) + lane;
            const float4 x0 = in4[base];
            const float4 t0 = tg4[base];
            const float4 x1 = in4[base + 1 * (D_COLS / 4)];
            const float4 t1 = tg4[base + 1 * (D_COLS / 4)];
            const float4 x2 = in4[base + 2 * (D_COLS / 4)];
            const float4 t2 = tg4[base + 2 * (D_COLS / 4)];
            const float4 x3 = in4[base + 3 * (D_COLS / 4)];
            const float4 t3 = tg4[base + 3 * (D_COLS / 4)];

            float d;
            d = x0.x - t0.x; rp0 += d * d;  d = x0.x + t0.x; rn0 += d * d;
            d = x0.y - t0.y; rp0 += d * d;  d = x0.y + t0.y; rn0 += d * d;
            d = x0.z - t0.z; rp0 += d * d;  d = x0.z + t0.z; rn0 += d * d;
            d = x0.w - t0.w; rp0 += d * d;  d = x0.w + t0.w; rn0 += d * d;

            d = x1.x - t1.x; rp1 += d * d;  d = x1.x + t1.x; rn1 += d * d;
            d = x1.y - t1.y; rp1 += d * d;  d = x1.y + t1.y; rn1 += d * d;
            d = x1.z - t1.z; rp1 += d * d;  d = x1.z + t1.z; rn1 += d * d;
            d = x1.w - t1.w; rp1 += d * d;  d = x1.w + t1.w; rn1 += d * d;

            d = x2.x - t2.x; rp2 += d * d;  d = x2.x + t2.x; rn2 += d * d;
            d = x2.y - t2.y; rp2 += d * d;  d = x2.y + t2.y; rn2 += d * d;
            d = x2.z - t2.z; rp2 += d * d;  d = x2.z + t2.z; rn2 += d * d;
            d = x2.w - t2.w; rp2 += d * d;  d = x2.w + t2.w; rn2 += d * d;

            d = x3.x - t3.x; rp3 += d * d;  d = x3.x + t3.x; rn3 += d * d;
            d = x3.y - t3.y; rp3 += d * d;  d = x3.y + t3.y; rn3 += d * d;
            d = x3.z - t3.z; rp3 += d * d;  d = x3.z + t3.z; rn3 += d * d;
            d = x3.w - t3.w; rp3 += d * d;  d = x3.w + t3.w; rn3 += d * d;
        }
        float rp = (rp0 + rp1) + (rp2 + rp3);
        float rn = (rn0 + rn1) + (rn2 + rn3);
        #pragma unroll
        for (int off = 32; off; off >>= 1) {
            rp += __shfl_down(rp, off);
            rn += __shfl_down(rn, off);
        }
        if (lane == 0) {
            atomicAdd(&lacc[b0 * 2 + 0], rp);   // LDS atomic
            atomicAdd(&lacc[b0 * 2 + 1], rn);
        }
    } else {
        // ---- slow path: chunk straddles a segment boundary (<=15 waves) ----
        for (int i = 0; i < ROWS_PER_WAVE; ++i) {
            const long r = row0 + i;
            const int b = batch[r];
            const float4 x = in4[r * (D_COLS / 4) + lane];
            const float4 t = tg4[r * (D_COLS / 4) + lane];
            float d;
            float p = 0.f, n = 0.f;
            d = x.x - t.x; p += d * d;  d = x.x + t.x; n += d * d;
            d = x.y - t.y; p += d * d;  d = x.y + t.y; n += d * d;
            d = x.z - t.z; p += d * d;  d = x.z + t.z; n += d * d;
            d = x.w - t.w; p += d * d;  d = x.w + t.w; n += d * d;
            #pragma unroll
            for (int off = 32; off; off >>= 1) {
                p += __shfl_down(p, off);
                n += __shfl_down(n, off);
            }
            if (lane == 0) {
                atomicAdd(&lacc[b * 2 + 0], p);
                atomicAdd(&lacc[b * 2 + 1], n);
            }
        }
    }

    __syncthreads();
    if (tid < B_SEG * 2) {
        acc[(long)blockIdx.x * (B_SEG * 2) + tid] = lacc[tid];  // 128 B store
    }
    __threadfence();          // make this block's partial visible device-wide
    if (tid == 0) {
        isLast = (atomicAdd(ticket, 1) == NBLK - 1);
    }
    __syncthreads();
    if (!isLast) return;

    // ---- last-arriving block: reduce acc[NBLK][32] -> out ----
    __threadfence();          // acquire: order reads after ticket observation
    const int val = tid & 31;
    const int grp = tid >> 5;             // 0..15
    float s = 0.f;
    for (int bl = grp; bl < NBLK; bl += 16)
        s += acc[bl * (B_SEG * 2) + val]; // wave reads 2 contiguous 128B lines
    sums[grp][val] = s;
    __syncthreads();
    if (tid < 64) {
        float total = 0.f;
        if (tid < B_SEG * 2) {
            #pragma unroll
            for (int g = 0; g < 16; ++g)
                total += sums[g][tid];
        }
        const float partner = __shfl_xor(total, 1);
        const float m = fminf(total, partner);
        float contrib = ((tid < B_SEG * 2) && ((tid & 1) == 0)) ? m : 0.f;
        #pragma unroll
        for (int off = 32; off; off >>= 1)
            contrib += __shfl_down(contrib, off);
        if (tid == 0) {
            out[0] = contrib;
            atomicExch(ticket, 0);   // reset for next graph replay
        }
    }
}

extern "C" void kernel_launch(void* const* d_in, const int* in_sizes, int n_in,
                              void* d_out, int out_size, void* d_ws, size_t ws_size,
                              hipStream_t stream) {
    const float* input  = (const float*)d_in[0];
    const float* target = (const float*)d_in[1];
    const int*   batch  = (const int*)d_in[2];
    float* acc    = (float*)d_ws;                               // 128 KB partials
    int*   ticket = (int*)((char*)d_ws + NBLK * B_SEG * 2 * sizeof(float));

    // ticket must start at 0 (d_ws is poisoned 0xAA once before timing);
    // the last block resets it to 0 for subsequent replays, this memset makes
    // the very first timed call correct too.
    hipMemsetAsync(ticket, 0, sizeof(int), stream);

    umse_fused<<<NBLK, BLK_THREADS, 0, stream>>>(input, target, batch, acc,
                                                 ticket, (float*)d_out);
}

// Round 6
// 56.324 us; speedup vs baseline: 5.2320x; 5.2320x over previous
//
#include <hip/hip_runtime.h>

#define N_ROWS 131072
#define D_COLS 256
#define B_SEG  16
#define ROWS_PER_WAVE 16
#define NSLOT 64   // accumulator slots, each 32 floats = 128 B (own cache line)

// One wave (64 lanes) handles ROWS_PER_WAVE contiguous rows.
// Lane l loads float4 at column 4*l: 64 lanes * 16B = 256 floats = one row.
// Fast path stages 8 rows of input+target into registers (16 independent
// dwordx4 loads in flight) before consuming.
__global__ __launch_bounds__(256) void umse_main(
    const float* __restrict__ input,
    const float* __restrict__ target,
    const int*   __restrict__ batch,
    float*       __restrict__ acc /* [NSLOT][B_SEG*2] */) {

    const int wave = (blockIdx.x * blockDim.x + threadIdx.x) >> 6;
    const int lane = threadIdx.x & 63;
    const int row0 = wave * ROWS_PER_WAVE;
    float* __restrict__ slot = acc + (blockIdx.x & (NSLOT - 1)) * (B_SEG * 2);

    const float4* __restrict__ in4 = (const float4*)input;
    const float4* __restrict__ tg4 = (const float4*)target;

    const int b0 = batch[row0];
    const int b1 = batch[row0 + ROWS_PER_WAVE - 1];

    if (b0 == b1) {
        // ---- fast path: whole chunk in one segment (8177+ of 8192 waves) ----
        float rp0 = 0.f, rn0 = 0.f, rp1 = 0.f, rn1 = 0.f;
        float rp2 = 0.f, rn2 = 0.f, rp3 = 0.f, rn3 = 0.f;
        #pragma unroll
        for (int half = 0; half < 2; ++half) {
            const int base = (row0 + half * 8) * (D_COLS / 4) + lane;
            float4 xa[8], ta[8];
            #pragma unroll
            for (int i = 0; i < 8; ++i) xa[i] = in4[base + i * (D_COLS / 4)];
            #pragma unroll
            for (int i = 0; i < 8; ++i) ta[i] = tg4[base + i * (D_COLS / 4)];
            #pragma unroll
            for (int i = 0; i < 8; ++i) {
                float d;
                d = xa[i].x - ta[i].x; rp0 += d * d;  d = xa[i].x + ta[i].x; rn0 += d * d;
                d = xa[i].y - ta[i].y; rp1 += d * d;  d = xa[i].y + ta[i].y; rn1 += d * d;
                d = xa[i].z - ta[i].z; rp2 += d * d;  d = xa[i].z + ta[i].z; rn2 += d * d;
                d = xa[i].w - ta[i].w; rp3 += d * d;  d = xa[i].w + ta[i].w; rn3 += d * d;
            }
        }
        float rp = (rp0 + rp1) + (rp2 + rp3);
        float rn = (rn0 + rn1) + (rn2 + rn3);
        #pragma unroll
        for (int off = 32; off; off >>= 1) {
            rp += __shfl_down(rp, off);
            rn += __shfl_down(rn, off);
        }
        if (lane == 0) {
            atomicAdd(&slot[b0 * 2 + 0], rp);
            atomicAdd(&slot[b0 * 2 + 1], rn);
        }
    } else {
        // ---- slow path: chunk straddles a segment boundary (<=15 waves) ----
        for (int i = 0; i < ROWS_PER_WAVE; ++i) {
            const int r = row0 + i;
            const int b = batch[r];
            const float4 x = in4[r * (D_COLS / 4) + lane];
            const float4 t = tg4[r * (D_COLS / 4) + lane];
            float d;
            float p = 0.f, n = 0.f;
            d = x.x - t.x; p += d * d;  d = x.x + t.x; n += d * d;
            d = x.y - t.y; p += d * d;  d = x.y + t.y; n += d * d;
            d = x.z - t.z; p += d * d;  d = x.z + t.z; n += d * d;
            d = x.w - t.w; p += d * d;  d = x.w + t.w; n += d * d;
            #pragma unroll
            for (int off = 32; off; off >>= 1) {
                p += __shfl_down(p, off);
                n += __shfl_down(n, off);
            }
            if (lane == 0) {
                atomicAdd(&slot[b * 2 + 0], p);
                atomicAdd(&slot[b * 2 + 1], n);
            }
        }
    }
}

// Reduce [NSLOT][32] -> out = sum_b min(lp[b], ln[b]). One wave.
__global__ void umse_final(const float* __restrict__ acc, float* __restrict__ out) {
    const int lane = threadIdx.x;  // 0..63
    float s = 0.f;
    if (lane < B_SEG * 2) {
        #pragma unroll
        for (int sl = 0; sl < NSLOT; ++sl)
            s += acc[sl * (B_SEG * 2) + lane];
    }
    const float partner = __shfl_xor(s, 1);
    const float m = fminf(s, partner);              // both lanes of a pair hold the min
    float contrib = ((lane < B_SEG * 2) && ((lane & 1) == 0)) ? m : 0.f;
    #pragma unroll
    for (int off = 32; off; off >>= 1)
        contrib += __shfl_down(contrib, off);
    if (lane == 0) out[0] = contrib;
}

extern "C" void kernel_launch(void* const* d_in, const int* in_sizes, int n_in,
                              void* d_out, int out_size, void* d_ws, size_t ws_size,
                              hipStream_t stream) {
    const float* input  = (const float*)d_in[0];
    const float* target = (const float*)d_in[1];
    const int*   batch  = (const int*)d_in[2];
    float* acc = (float*)d_ws;   // NSLOT*32*4 = 8 KB of scratch

    // zero the slotted accumulators every call (d_ws is not re-poisoned between replays)
    hipMemsetAsync(acc, 0, NSLOT * B_SEG * 2 * sizeof(float), stream);

    const int waves  = N_ROWS / ROWS_PER_WAVE;      // 8192
    const int blocks = waves * 64 / 256;            // 2048 blocks, 256 thr
    umse_main<<<blocks, 256, 0, stream>>>(input, target, batch, acc);
    umse_final<<<1, 64, 0, stream>>>(acc, (float*)d_out);
}